// Round 10
// baseline (232.568 us; speedup 1.0000x reference)
//
#include <hip/hip_runtime.h>
#include <stdint.h>

typedef _Float16 f16;
typedef f16 half8 __attribute__((ext_vector_type(8)));
typedef f16 half4 __attribute__((ext_vector_type(4)));
typedef float floatx4 __attribute__((ext_vector_type(4)));

#define MFMA_F16(A, B, Cc) __builtin_amdgcn_mfma_f32_16x16x32_f16((A), (B), (Cc), 0, 0, 0)

// Problem constants: B=4, H=W=64 -> N=4096, C=256, d=32
static constexpr int NB  = 4;
static constexpr int NN  = 4096;
static constexpr int NC  = 256;
static constexpr int ND  = 32;
static constexpr int PIX = NB * NN;  // 16384
static constexpr int NS  = 4;        // key splits (NS=6 failed: reg-locked 2 blocks/CU)
static constexpr int KS  = NN / NS;  // 1024 keys per split

// Device-global scratch. Fully rewritten every launch.
__device__ f16 g_WbT[320 * 256];              // [j][k]
__device__ f16 g_Qh[(size_t)PIX * ND];        // [row][32], pre-scaled by log2(e)
__device__ f16 g_Kh[(size_t)PIX * ND];        // [row][32]
__device__ f16 g_VbT[(size_t)NB * NC * NN];   // [b][c][n]
__device__ f16 g_Of[(size_t)NS * PIX * NC];   // per-split normalized O
__device__ float g_m[NS * PIX];               // per-split max (log2 domain)
__device__ float g_l[NS * PIX];               // per-split denom

__device__ inline void gl2lds16(const f16* g, f16* l) {
  __builtin_amdgcn_global_load_lds(
      (const __attribute__((address_space(1))) void*)g,
      (__attribute__((address_space(3))) void*)l, 16, 0, 0);
}

// ---------------------------------------------------------------------------
__global__ __launch_bounds__(256) void prep_weights(const float* __restrict__ wq,
                                                    const float* __restrict__ wk,
                                                    const float* __restrict__ wv) {
  const int tid = blockIdx.x * 256 + threadIdx.x;
  if (tid >= 320 * 256) return;
  const int j = tid >> 8;
  const int k = tid & 255;
  float v;
  if (j < 32)      v = wq[k * 32 + j];
  else if (j < 64) v = wk[k * 32 + (j - 32)];
  else             v = wv[k * 256 + (j - 64)];
  g_WbT[j * 256 + k] = (f16)v;
}

// ---------------------------------------------------------------------------
// QKV projection (R7 version, best measured; R9's in-kernel weight cvt
// regressed 16 us via a 32-way ds_write bank conflict — reverted).
// 4-way j-split, dbuf stage, one barrier per K-chunk, weights via
// global_load_lds, x issue-early/write-late.
__global__ __launch_bounds__(256, 4) void proj_qkv(const float* __restrict__ x,
                                                   const float* __restrict__ bq,
                                                   const float* __restrict__ bk,
                                                   const float* __restrict__ bv) {
  __shared__ f16 xs[2][64 * 32];    // 8 KB   [buf][row][k-chunk]
  __shared__ f16 wsT[2][80 * 32];   // 10 KB  [buf][j-local][k-chunk]
  __shared__ f16 vt[80 * 64];       // 10 KB  [v-col-local][pixel]

  const int tid  = threadIdx.x;
  const int lane = tid & 63;
  const int wid  = tid >> 6;
  const int qd   = lane >> 4;
  const int c16  = lane & 15;
  const int p0   = blockIdx.x * 64;
  const int q    = blockIdx.y;
  const int j0   = q * 80;
  const floatx4 zero4 = {0.f, 0.f, 0.f, 0.f};

  // staging geometry
  const int sr = tid >> 2, sg = tid & 3;                 // xs: row, 8-col group
  const float* xsrc = x + (size_t)(p0 + sr) * NC + sg * 8;
  const f16* wsrc = g_WbT + (size_t)(j0 + (lane >> 2)) * 256 + (lane & 3) * 8;

  floatx4 acc[5];
#pragma unroll
  for (int i = 0; i < 5; ++i) acc[i] = zero4;

  // ---- prologue: full stage of chunk 0 into buf 0 ----
  {
    const floatx4* s4 = (const floatx4*)xsrc;
    const floatx4 xa = s4[0], xb = s4[1];
#pragma unroll
    for (int grp = wid; grp < 5; grp += 4)
      gl2lds16(wsrc + (size_t)grp * 16 * 256, &wsT[0][grp * 512]);
    half8 h;
    h[0] = (f16)xa[0]; h[1] = (f16)xa[1]; h[2] = (f16)xa[2]; h[3] = (f16)xa[3];
    h[4] = (f16)xb[0]; h[5] = (f16)xb[1]; h[6] = (f16)xb[2]; h[7] = (f16)xb[3];
    *(half8*)&xs[0][sr * 32 + sg * 8] = h;
  }

  for (int c = 0; c < 8; ++c) {
    const int cur = c & 1;
    __syncthreads();  // buf[cur] staged (vmcnt+lgkm drained); buf[cur^1] free

    // issue next chunk's loads early (x -> regs; weights -> LDS direct)
    floatx4 xa, xb;
    const bool pf = (c < 7);
    if (pf) {
      const floatx4* s4 = (const floatx4*)(xsrc + (c + 1) * 32);
      xa = s4[0]; xb = s4[1];
#pragma unroll
      for (int grp = wid; grp < 5; grp += 4)
        gl2lds16(wsrc + (size_t)grp * 16 * 256 + (c + 1) * 32,
                 &wsT[cur ^ 1][grp * 512]);
    }

    // compute chunk c from buf[cur]
    const half8 a = *(const half8*)&xs[cur][(wid * 16 + c16) * 32 + qd * 8];
#pragma unroll
    for (int nt = 0; nt < 5; ++nt) {
      const half8 bfr = *(const half8*)&wsT[cur][(nt * 16 + c16) * 32 + qd * 8];
      acc[nt] = MFMA_F16(a, bfr, acc[nt]);
    }

    // write-late: cvt + ds_write of next x-tile (after MFMAs)
    if (pf) {
      half8 h;
      h[0] = (f16)xa[0]; h[1] = (f16)xa[1]; h[2] = (f16)xa[2]; h[3] = (f16)xa[3];
      h[4] = (f16)xb[0]; h[5] = (f16)xb[1]; h[6] = (f16)xb[2]; h[7] = (f16)xb[3];
      *(half8*)&xs[cur ^ 1][sr * 32 + sg * 8] = h;
    }
  }

  // ---- epilogue: bias; Q/K stores (quarter 0), V via LDS transpose ----
#pragma unroll
  for (int nt = 0; nt < 5; ++nt) {
    const int j = j0 + nt * 16 + c16;
    const float bias = (j < 32) ? bq[j] : (j < 64) ? bk[j - 32] : bv[j - 64];
#pragma unroll
    for (int r = 0; r < 4; ++r) {
      const int rl = wid * 16 + qd * 4 + r;
      const int p  = p0 + rl;
      const float val = acc[nt][r] + bias;
      if (j < 32) {
        g_Qh[(size_t)p * ND + j] = (f16)(val * 1.44269504f);  // log2(e)
      } else if (j < 64) {
        g_Kh[(size_t)p * ND + (j - 32)] = (f16)val;
      } else {
        const int vloc = (q == 0) ? (nt * 16 + c16 - 64) : (nt * 16 + c16);
        vt[vloc * 64 + rl] = (f16)val;
      }
    }
  }
  __syncthreads();

  const int b    = p0 >> 12;
  const int n0   = p0 & (NN - 1);
  const int vt0  = q ? (80 * q - 64) : 0;   // first global V col of this quarter
  const int ncol = q ? 80 : 16;
  for (int i = tid; i < ncol * 8; i += 256) {
    const int cc = i >> 3, m = i & 7;
    *(half8*)(g_VbT + ((size_t)(b * NC + vt0 + cc)) * NN + n0 + m * 8) =
        *(const half8*)&vt[cc * 64 + m * 8];
  }
}

// ---------------------------------------------------------------------------
// Flash attention, round-10: BARRIER-FREE waves, V direct from L2.
// Rationale: pipe accounting of the frozen kernel shows LDS ~65% busy (32
// ds_read_b128 of V per wave-iter) — the top consumer — and the two per-iter
// barriers exist ONLY to coordinate the shared vsT staging. But the PV
// B-fragment is 16 contiguous bytes of g_VbT[b][c][n], and a wave's 64 lanes
// read 16 full 64B lines (coalesced); V per (b,s) is 512 KB, L2-resident
// (R2: ~99% L2 hit on this stream). So V is read straight from global:
// vsT deleted, staging deleted, BOTH barriers deleted. ps is wave-private
// (within-wave lgkmcnt ordering) -> waves free-run at independent phases,
// self-hiding latency instead of phase-aligned pipe bursts.
// Q/K frags, softmax, ps swizzle, epilogue: byte-identical to the verified
// structure. Still reg-capped at 2 blocks/CU (116 VGPR + 128 AGPR).
__global__ __launch_bounds__(256, 2) void attn_split(void) {
  __shared__ f16 ps[4][2][16 * 64];    // 16 KB  [wave][qgrp][q][64 keys], swizzled

  const int tid  = threadIdx.x;
  const int lane = tid & 63;
  const int wid  = tid >> 6;
  const int qd   = lane >> 4;
  const int c16  = lane & 15;
  const int b    = blockIdx.y;
  const int s    = blockIdx.z;
  const int q0   = blockIdx.x * 128 + wid * 32;
  const int sx7  = c16 & 7;  // row&7 for this lane's ps reads
  const floatx4 zero4 = {0.f, 0.f, 0.f, 0.f};

  // V base for this batch; PV reads 16B frags at (b*NC + c)*NN + k.
  const f16* vbase = g_VbT + (size_t)(b * NC) * NN;

  // Q fragments (B-operand)
  half8 qf[2];
#pragma unroll
  for (int g = 0; g < 2; ++g)
    qf[g] = *(const half8*)(g_Qh + ((size_t)(b * NN + q0 + g * 16 + c16)) * ND + qd * 8);

  floatx4 acc[2][16];
#pragma unroll
  for (int g = 0; g < 2; ++g)
#pragma unroll
    for (int i = 0; i < 16; ++i) acc[g][i] = zero4;
  float m_i[2] = {-1e30f, -1e30f};
  float l_p[2] = {0.f, 0.f};

  const int kbeg = s * KS, kend = (s + 1) * KS;

  // prologue: K(kbeg) -> regs
  half8 kreg[4];
#pragma unroll
  for (int a = 0; a < 4; ++a)
    kreg[a] = *(const half8*)(g_Kh + ((size_t)(b * NN + kbeg + a * 16 + c16)) * ND + qd * 8);

  for (int k0 = kbeg; k0 < kend; k0 += 64) {
    // ---- S^T = K * Q^T from registers ----
    floatx4 st[2][4];
#pragma unroll
    for (int g = 0; g < 2; ++g)
#pragma unroll
      for (int a = 0; a < 4; ++a) st[g][a] = MFMA_F16(kreg[a], qf[g], zero4);

    // ---- lazy max (overshoot +5, log2 domain) ----
    float tm[2];
#pragma unroll
    for (int g = 0; g < 2; ++g) {
      float t0 = fmaxf(fmaxf(st[g][0][0], st[g][0][1]), fmaxf(st[g][0][2], st[g][0][3]));
      float t1 = fmaxf(fmaxf(st[g][1][0], st[g][1][1]), fmaxf(st[g][1][2], st[g][1][3]));
      float t2 = fmaxf(fmaxf(st[g][2][0], st[g][2][1]), fmaxf(st[g][2][2], st[g][2][3]));
      float t3 = fmaxf(fmaxf(st[g][3][0], st[g][3][1]), fmaxf(st[g][3][2], st[g][3][3]));
      tm[g] = fmaxf(fmaxf(t0, t1), fmaxf(t2, t3));
    }
    if (__any(tm[0] > m_i[0] || tm[1] > m_i[1])) {
#pragma unroll
      for (int g = 0; g < 2; ++g) {
        float tr = tm[g];
        tr = fmaxf(tr, __shfl_xor(tr, 16));
        tr = fmaxf(tr, __shfl_xor(tr, 32));
        const float m_new = (tr > m_i[g]) ? tr + 5.0f : m_i[g];
        const float alpha = exp2f(m_i[g] - m_new);
        m_i[g] = m_new;
        l_p[g] *= alpha;
        float a4[4];
#pragma unroll
        for (int r = 0; r < 4; ++r) a4[r] = __shfl(alpha, qd * 4 + r);
#pragma unroll
        for (int ct = 0; ct < 16; ++ct)
#pragma unroll
          for (int r = 0; r < 4; ++r) acc[g][ct][r] *= a4[r];
      }
    }

    // ---- P = exp2(s - m), per-lane partial l, swizzled ps write ----
    // key = a*16 + qd*4  -> chunk a*2+(qd>>1), sub-offset (qd&1)*4
#pragma unroll
    for (int g = 0; g < 2; ++g) {
      float ts = 0.f;
#pragma unroll
      for (int a = 0; a < 4; ++a) {
        half4 h;
#pragma unroll
        for (int r = 0; r < 4; ++r) {
          const float p = exp2f(st[g][a][r] - m_i[g]);
          ts += p;
          h[r] = (f16)p;
        }
        const int pc = ((a * 2 + (qd >> 1)) ^ sx7) * 8 + (qd & 1) * 4;
        *(half4*)&ps[wid][g][c16 * 64 + pc] = h;
      }
      l_p[g] += ts;
    }

    // ---- prefetch K(next) into regs (latency covered by PV MFMAs) ----
    const int k0n = (k0 + 64 < kend) ? (k0 + 64) : kbeg;
    half8 knew[4];
#pragma unroll
    for (int a = 0; a < 4; ++a)
      knew[a] = *(const half8*)(g_Kh + ((size_t)(b * NN + k0n + a * 16 + c16)) * ND + qd * 8);

    // ---- PV: O += P * V, 64 MFMAs; P from wave-private LDS, V from L2 ----
    half8 pa[2][2];
#pragma unroll
    for (int g = 0; g < 2; ++g)
#pragma unroll
      for (int kh = 0; kh < 2; ++kh)
        pa[g][kh] = *(const half8*)&ps[wid][g][c16 * 64 + ((kh * 4 + qd) ^ sx7) * 8];
#pragma unroll
    for (int ct = 0; ct < 16; ++ct) {
#pragma unroll
      for (int kh = 0; kh < 2; ++kh) {
        const half8 bfr = *(const half8*)(
            vbase + (size_t)(ct * 16 + c16) * NN + k0 + (kh * 4 + qd) * 8);
        acc[0][ct] = MFMA_F16(pa[0][kh], bfr, acc[0][ct]);
        acc[1][ct] = MFMA_F16(pa[1][kh], bfr, acc[1][ct]);
      }
    }
#pragma unroll
    for (int a = 0; a < 4; ++a) kreg[a] = knew[a];
  }

  // ---- epilogue ----
#pragma unroll
  for (int g = 0; g < 2; ++g) {
    float l = l_p[g];
    l += __shfl_xor(l, 16);
    l += __shfl_xor(l, 32);
    if (qd == 0) {
      const int row = b * NN + q0 + g * 16 + c16;
      g_m[s * PIX + row] = m_i[g];
      g_l[s * PIX + row] = l;
    }
    float linv[4];
#pragma unroll
    for (int r = 0; r < 4; ++r) linv[r] = 1.0f / __shfl(l, qd * 4 + r);
#pragma unroll
    for (int ct = 0; ct < 16; ++ct)
#pragma unroll
      for (int r = 0; r < 4; ++r) {
        const int qrow = q0 + g * 16 + qd * 4 + r;
        const int c = ct * 16 + c16;
        g_Of[((size_t)(s * PIX + b * NN + qrow)) * NC + c] = (f16)(acc[g][ct][r] * linv[r]);
      }
  }
}

// ---------------------------------------------------------------------------
// Merge NS partials (log2 domain): w_s = l_s * 2^(m_s - M) / den.
// 16B loads (half8 per split), 8 rows/block, grid PIX/8.
__global__ __launch_bounds__(256) void combine(const float* __restrict__ x,
                                               float* __restrict__ out) {
  const int tid  = threadIdx.x;
  const int lane = tid & 63;
  const int wid  = tid >> 6;
  const int row  = blockIdx.x * 8 + wid * 2 + (lane >> 5);
  const int c    = (lane & 31) * 8;

  float m[NS], l[NS], M = -1e30f;
#pragma unroll
  for (int s = 0; s < NS; ++s) {
    m[s] = g_m[s * PIX + row];
    l[s] = g_l[s * PIX + row];
    M = fmaxf(M, m[s]);
  }
  float w[NS], den = 0.f;
#pragma unroll
  for (int s = 0; s < NS; ++s) { w[s] = l[s] * exp2f(m[s] - M); den += w[s]; }
  const float inv = 1.0f / den;

  float a[8];
#pragma unroll
  for (int j = 0; j < 8; ++j) a[j] = 0.f;
#pragma unroll
  for (int s = 0; s < NS; ++s) {
    const half8 h = *(const half8*)&g_Of[((size_t)(s * PIX + row)) * NC + c];
    const float ws = w[s] * inv;
#pragma unroll
    for (int j = 0; j < 8; ++j) a[j] += ws * (float)h[j];
  }
  const floatx4 x0 = *(const floatx4*)&x[(size_t)row * NC + c];
  const floatx4 x1 = *(const floatx4*)&x[(size_t)row * NC + c + 4];
  floatx4 o0, o1;
#pragma unroll
  for (int j = 0; j < 4; ++j) { o0[j] = a[j] + x0[j]; o1[j] = a[j + 4] + x1[j]; }
  *(floatx4*)&out[(size_t)row * NC + c] = o0;
  *(floatx4*)&out[(size_t)row * NC + c + 4] = o1;
}

// ---------------------------------------------------------------------------
extern "C" void kernel_launch(void* const* d_in, const int* in_sizes, int n_in,
                              void* d_out, int out_size, void* d_ws, size_t ws_size,
                              hipStream_t stream) {
  (void)in_sizes; (void)n_in; (void)d_ws; (void)ws_size; (void)out_size;
  const float* x  = (const float*)d_in[0];
  const float* wq = (const float*)d_in[1];
  const float* bq = (const float*)d_in[2];
  const float* wk = (const float*)d_in[3];
  const float* bk = (const float*)d_in[4];
  const float* wv = (const float*)d_in[5];
  const float* bv = (const float*)d_in[6];
  float* out = (float*)d_out;

  hipLaunchKernelGGL(prep_weights, dim3(320), dim3(256), 0, stream, wq, wk, wv);
  hipLaunchKernelGGL(proj_qkv, dim3(256, 4), dim3(256), 0, stream, x, bq, bk, bv);
  hipLaunchKernelGGL(attn_split, dim3(NN / 128, NB, NS), dim3(256), 0, stream);
  hipLaunchKernelGGL(combine, dim3(PIX / 8), dim3(256), 0, stream, x, out);
}

// Round 11
// 161.310 us; speedup vs baseline: 1.4417x; 1.4417x over previous
//
#include <hip/hip_runtime.h>
#include <stdint.h>

typedef _Float16 f16;
typedef f16 half8 __attribute__((ext_vector_type(8)));
typedef f16 half4 __attribute__((ext_vector_type(4)));
typedef float floatx4 __attribute__((ext_vector_type(4)));

#define MFMA_F16(A, B, Cc) __builtin_amdgcn_mfma_f32_16x16x32_f16((A), (B), (Cc), 0, 0, 0)

// Problem constants: B=4, H=W=64 -> N=4096, C=256, d=32
static constexpr int NB  = 4;
static constexpr int NN  = 4096;
static constexpr int NC  = 256;
static constexpr int ND  = 32;
static constexpr int PIX = NB * NN;  // 16384
static constexpr int NS  = 4;        // key splits (NS=6 failed: reg-locked 2 blocks/CU)
static constexpr int KS  = NN / NS;  // 1024 keys per split

// Device-global scratch. Fully rewritten every launch.
__device__ f16 g_WbT[320 * 256];              // [j][k]
__device__ f16 g_Qh[(size_t)PIX * ND];        // [row][32], pre-scaled by log2(e)
__device__ f16 g_Kh[(size_t)PIX * ND];        // [row][32]
__device__ f16 g_VbT[(size_t)NB * NC * NN];   // [b][c][n]
__device__ f16 g_Of[(size_t)NS * PIX * NC];   // per-split normalized O
__device__ float g_m[NS * PIX];               // per-split max (log2 domain)
__device__ float g_l[NS * PIX];               // per-split denom

__device__ inline void gl2lds16(const f16* g, f16* l) {
  __builtin_amdgcn_global_load_lds(
      (const __attribute__((address_space(1))) void*)g,
      (__attribute__((address_space(3))) void*)l, 16, 0, 0);
}

// ---------------------------------------------------------------------------
__global__ __launch_bounds__(256) void prep_weights(const float* __restrict__ wq,
                                                    const float* __restrict__ wk,
                                                    const float* __restrict__ wv) {
  const int tid = blockIdx.x * 256 + threadIdx.x;
  if (tid >= 320 * 256) return;
  const int j = tid >> 8;
  const int k = tid & 255;
  float v;
  if (j < 32)      v = wq[k * 32 + j];
  else if (j < 64) v = wk[k * 32 + (j - 32)];
  else             v = wv[k * 256 + (j - 64)];
  g_WbT[j * 256 + k] = (f16)v;
}

// ---------------------------------------------------------------------------
// QKV projection (R7 version, best measured). 4-way j-split, dbuf stage,
// one barrier per K-chunk, weights via global_load_lds, x issue-early/
// write-late. quarter q: j in [80q, 80q+80). q0: Q(0..31) K(32..63)
// V(0..15); q1: V(16..95); q2: V(96..175); q3: V(176..255).
__global__ __launch_bounds__(256, 4) void proj_qkv(const float* __restrict__ x,
                                                   const float* __restrict__ bq,
                                                   const float* __restrict__ bk,
                                                   const float* __restrict__ bv) {
  __shared__ f16 xs[2][64 * 32];    // 8 KB   [buf][row][k-chunk]
  __shared__ f16 wsT[2][80 * 32];   // 10 KB  [buf][j-local][k-chunk]
  __shared__ f16 vt[80 * 64];       // 10 KB  [v-col-local][pixel]

  const int tid  = threadIdx.x;
  const int lane = tid & 63;
  const int wid  = tid >> 6;
  const int qd   = lane >> 4;
  const int c16  = lane & 15;
  const int p0   = blockIdx.x * 64;
  const int q    = blockIdx.y;
  const int j0   = q * 80;
  const floatx4 zero4 = {0.f, 0.f, 0.f, 0.f};

  // staging geometry
  const int sr = tid >> 2, sg = tid & 3;                 // xs: row, 8-col group
  const float* xsrc = x + (size_t)(p0 + sr) * NC + sg * 8;
  const f16* wsrc = g_WbT + (size_t)(j0 + (lane >> 2)) * 256 + (lane & 3) * 8;

  floatx4 acc[5];
#pragma unroll
  for (int i = 0; i < 5; ++i) acc[i] = zero4;

  // ---- prologue: full stage of chunk 0 into buf 0 ----
  {
    const floatx4* s4 = (const floatx4*)xsrc;
    const floatx4 xa = s4[0], xb = s4[1];
#pragma unroll
    for (int grp = wid; grp < 5; grp += 4)
      gl2lds16(wsrc + (size_t)grp * 16 * 256, &wsT[0][grp * 512]);
    half8 h;
    h[0] = (f16)xa[0]; h[1] = (f16)xa[1]; h[2] = (f16)xa[2]; h[3] = (f16)xa[3];
    h[4] = (f16)xb[0]; h[5] = (f16)xb[1]; h[6] = (f16)xb[2]; h[7] = (f16)xb[3];
    *(half8*)&xs[0][sr * 32 + sg * 8] = h;
  }

  for (int c = 0; c < 8; ++c) {
    const int cur = c & 1;
    __syncthreads();  // buf[cur] staged (vmcnt+lgkm drained); buf[cur^1] free

    // issue next chunk's loads early (x -> regs; weights -> LDS direct)
    floatx4 xa, xb;
    const bool pf = (c < 7);
    if (pf) {
      const floatx4* s4 = (const floatx4*)(xsrc + (c + 1) * 32);
      xa = s4[0]; xb = s4[1];
#pragma unroll
      for (int grp = wid; grp < 5; grp += 4)
        gl2lds16(wsrc + (size_t)grp * 16 * 256 + (c + 1) * 32,
                 &wsT[cur ^ 1][grp * 512]);
    }

    // compute chunk c from buf[cur]
    const half8 a = *(const half8*)&xs[cur][(wid * 16 + c16) * 32 + qd * 8];
#pragma unroll
    for (int nt = 0; nt < 5; ++nt) {
      const half8 bfr = *(const half8*)&wsT[cur][(nt * 16 + c16) * 32 + qd * 8];
      acc[nt] = MFMA_F16(a, bfr, acc[nt]);
    }

    // write-late: cvt + ds_write of next x-tile (after MFMAs)
    if (pf) {
      half8 h;
      h[0] = (f16)xa[0]; h[1] = (f16)xa[1]; h[2] = (f16)xa[2]; h[3] = (f16)xa[3];
      h[4] = (f16)xb[0]; h[5] = (f16)xb[1]; h[6] = (f16)xb[2]; h[7] = (f16)xb[3];
      *(half8*)&xs[cur ^ 1][sr * 32 + sg * 8] = h;
    }
  }

  // ---- epilogue: bias; Q/K stores (quarter 0), V via LDS transpose ----
#pragma unroll
  for (int nt = 0; nt < 5; ++nt) {
    const int j = j0 + nt * 16 + c16;
    const float bias = (j < 32) ? bq[j] : (j < 64) ? bk[j - 32] : bv[j - 64];
#pragma unroll
    for (int r = 0; r < 4; ++r) {
      const int rl = wid * 16 + qd * 4 + r;
      const int p  = p0 + rl;
      const float val = acc[nt][r] + bias;
      if (j < 32) {
        g_Qh[(size_t)p * ND + j] = (f16)(val * 1.44269504f);  // log2(e)
      } else if (j < 64) {
        g_Kh[(size_t)p * ND + (j - 32)] = (f16)val;
      } else {
        const int vloc = (q == 0) ? (nt * 16 + c16 - 64) : (nt * 16 + c16);
        vt[vloc * 64 + rl] = (f16)val;
      }
    }
  }
  __syncthreads();

  const int b    = p0 >> 12;
  const int n0   = p0 & (NN - 1);
  const int vt0  = q ? (80 * q - 64) : 0;   // first global V col of this quarter
  const int ncol = q ? 80 : 16;
  for (int i = tid; i < ncol * 8; i += 256) {
    const int cc = i >> 3, m = i & 7;
    *(half8*)(g_VbT + ((size_t)(b * NC + vt0 + cc)) * NN + n0 + m * 8) =
        *(const half8*)&vt[cc * 64 + m * 8];
  }
}

// ---------------------------------------------------------------------------
// Flash attention, round-11: frozen math/layout, COUNTED-WAIT sync.
// Closed branches: not HBM/barrier-count (R2), not occupancy (R8: ~244
// regs/wave -> 2 blocks/CU hard), V staging load-bearing (R10: direct-L2 V
// = 4x L2 traffic, 2x slower). Remaining identified stall: __syncthreads
// compiles to s_waitcnt vmcnt(0) lgkmcnt(0); at [B] it force-drains the
// K(t+1) prefetch that PV was supposed to cover, every iteration.
// Change (T4 mechanism): vsT double-buffered (R2-verified layout); ONE raw
// s_barrier per iter with an explicit vmcnt-only wait (no lgkm/exp drain);
// barrier [B] deleted (a wave's PV ds_reads are complete before it can
// reach the next barrier: the consuming MFMAs cannot issue otherwise);
// V-stage issue moved BEFORE PV (flight = PV+QK+softmax, was QK+softmax);
// K prefetch never drained. Cross-wave safety: barrier-per-iter bounds wave
// skew <1 iter, and the stage targets buf^1 which every wave finished
// reading before the barrier it just passed.
__global__ __launch_bounds__(256, 2) void attn_split(void) {
  __shared__ f16 vsT[2][256 * 64];     // 64 KB  [buf][c][64 keys], chunk-swizzled
  __shared__ f16 ps[4][2][16 * 64];    // 16 KB  [wave][qgrp][q][64 keys], swizzled

  const int tid  = threadIdx.x;
  const int lane = tid & 63;
  const int wid  = tid >> 6;
  const int qd   = lane >> 4;
  const int c16  = lane & 15;
  const int b    = blockIdx.y;
  const int s    = blockIdx.z;
  const int q0   = blockIdx.x * 128 + wid * 32;
  const int sx7  = c16 & 7;  // row&7 for this lane's reads
  const floatx4 zero4 = {0.f, 0.f, 0.f, 0.f};

  // Per-lane V staging source: wave wid stages c rows [wid*64, wid*64+64).
  // LDS dest of gl_lds is wave-uniform base + lane*16 (lane-linear), so the
  // XOR swizzle is applied to the GLOBAL source chunk instead.
  const int vrow = wid * 64 + (lane >> 3);
  const int vchk = (lane & 7) ^ ((lane >> 3) & 7);
  const f16* vlane = g_VbT + ((size_t)(b * NC + vrow)) * NN + vchk * 8;

  // Q fragments (B-operand)
  half8 qf[2];
#pragma unroll
  for (int g = 0; g < 2; ++g)
    qf[g] = *(const half8*)(g_Qh + ((size_t)(b * NN + q0 + g * 16 + c16)) * ND + qd * 8);

  floatx4 acc[2][16];
#pragma unroll
  for (int g = 0; g < 2; ++g)
#pragma unroll
    for (int i = 0; i < 16; ++i) acc[g][i] = zero4;
  float m_i[2] = {-1e30f, -1e30f};
  float l_p[2] = {0.f, 0.f};

  const int kbeg = s * KS, kend = (s + 1) * KS;

  // prologue: V(kbeg) async -> LDS buf0; K(kbeg) -> regs
  {
    f16* vdst = &vsT[0][(size_t)wid * 4096];
#pragma unroll
    for (int i = 0; i < 8; ++i)
      gl2lds16(vlane + kbeg + i * 8 * NN, vdst + i * 512);
  }
  half8 kreg[4];
#pragma unroll
  for (int a = 0; a < 4; ++a)
    kreg[a] = *(const half8*)(g_Kh + ((size_t)(b * NN + kbeg + a * 16 + c16)) * ND + qd * 8);

  for (int k0 = kbeg; k0 < kend; k0 += 64) {
    const int buf = ((k0 - kbeg) >> 6) & 1;

    // ---- S^T = K * Q^T from registers (no LDS dependency) ----
    floatx4 st[2][4];
#pragma unroll
    for (int g = 0; g < 2; ++g)
#pragma unroll
      for (int a = 0; a < 4; ++a) st[g][a] = MFMA_F16(kreg[a], qf[g], zero4);

    // ---- lazy max (overshoot +5, log2 domain) ----
    float tm[2];
#pragma unroll
    for (int g = 0; g < 2; ++g) {
      float t0 = fmaxf(fmaxf(st[g][0][0], st[g][0][1]), fmaxf(st[g][0][2], st[g][0][3]));
      float t1 = fmaxf(fmaxf(st[g][1][0], st[g][1][1]), fmaxf(st[g][1][2], st[g][1][3]));
      float t2 = fmaxf(fmaxf(st[g][2][0], st[g][2][1]), fmaxf(st[g][2][2], st[g][2][3]));
      float t3 = fmaxf(fmaxf(st[g][3][0], st[g][3][1]), fmaxf(st[g][3][2], st[g][3][3]));
      tm[g] = fmaxf(fmaxf(t0, t1), fmaxf(t2, t3));
    }
    if (__any(tm[0] > m_i[0] || tm[1] > m_i[1])) {
#pragma unroll
      for (int g = 0; g < 2; ++g) {
        float tr = tm[g];
        tr = fmaxf(tr, __shfl_xor(tr, 16));
        tr = fmaxf(tr, __shfl_xor(tr, 32));
        const float m_new = (tr > m_i[g]) ? tr + 5.0f : m_i[g];
        const float alpha = exp2f(m_i[g] - m_new);
        m_i[g] = m_new;
        l_p[g] *= alpha;
        float a4[4];
#pragma unroll
        for (int r = 0; r < 4; ++r) a4[r] = __shfl(alpha, qd * 4 + r);
#pragma unroll
        for (int ct = 0; ct < 16; ++ct)
#pragma unroll
          for (int r = 0; r < 4; ++r) acc[g][ct][r] *= a4[r];
      }
    }

    // ---- P = exp2(s - m), per-lane partial l, swizzled ps write ----
    // key = a*16 + qd*4  -> chunk a*2+(qd>>1), sub-offset (qd&1)*4
#pragma unroll
    for (int g = 0; g < 2; ++g) {
      float ts = 0.f;
#pragma unroll
      for (int a = 0; a < 4; ++a) {
        half4 h;
#pragma unroll
        for (int r = 0; r < 4; ++r) {
          const float p = exp2f(st[g][a][r] - m_i[g]);
          ts += p;
          h[r] = (f16)p;
        }
        const int pc = ((a * 2 + (qd >> 1)) ^ sx7) * 8 + (qd & 1) * 4;
        *(half4*)&ps[wid][g][c16 * 64 + pc] = h;
      }
      l_p[g] += ts;
    }

    // ---- [A] single sync: own V(k0) stages done (vmem only; no lgkm/exp
    // drain), then barrier -> all waves' V(k0) landed AND all waves done
    // reading vsT[buf^1] (their reads retired before arrival). ----
    asm volatile("s_waitcnt vmcnt(0)" ::: "memory");
    __builtin_amdgcn_s_barrier();

    // ---- prefetch K(next) into regs; stays IN FLIGHT across the whole
    // iteration (no drain anywhere until next iter's QK consumes it) ----
    const int k0n = (k0 + 64 < kend) ? (k0 + 64) : kbeg;
    half8 knew[4];
#pragma unroll
    for (int a = 0; a < 4; ++a)
      knew[a] = *(const half8*)(g_Kh + ((size_t)(b * NN + k0n + a * 16 + c16)) * ND + qd * 8);

    // ---- issue async V(k+1) -> buf^1 BEFORE PV (flight = PV+QK+softmax) ----
    if (k0 + 64 < kend) {
      f16* vdst = &vsT[buf ^ 1][(size_t)wid * 4096];
#pragma unroll
      for (int i = 0; i < 8; ++i)
        gl2lds16(vlane + (k0 + 64) + i * 8 * NN, vdst + i * 512);
    }

    // ---- PV: O += P * V, 64 MFMAs; swizzled reads from vsT[buf] ----
    half8 pa[2][2];
#pragma unroll
    for (int g = 0; g < 2; ++g)
#pragma unroll
      for (int kh = 0; kh < 2; ++kh)
        pa[g][kh] = *(const half8*)&ps[wid][g][c16 * 64 + ((kh * 4 + qd) ^ sx7) * 8];
#pragma unroll
    for (int ct = 0; ct < 16; ++ct) {
#pragma unroll
      for (int kh = 0; kh < 2; ++kh) {
        const half8 bfr =
            *(const half8*)&vsT[buf][(ct * 16 + c16) * 64 + ((kh * 4 + qd) ^ sx7) * 8];
        acc[0][ct] = MFMA_F16(pa[0][kh], bfr, acc[0][ct]);
        acc[1][ct] = MFMA_F16(pa[1][kh], bfr, acc[1][ct]);
      }
    }
    // (no second barrier: stage of the NEXT iter happens only after the
    // next [A], which every wave reaches with its PV reads retired)

#pragma unroll
    for (int a = 0; a < 4; ++a) kreg[a] = knew[a];
  }

  // ---- epilogue ----
#pragma unroll
  for (int g = 0; g < 2; ++g) {
    float l = l_p[g];
    l += __shfl_xor(l, 16);
    l += __shfl_xor(l, 32);
    if (qd == 0) {
      const int row = b * NN + q0 + g * 16 + c16;
      g_m[s * PIX + row] = m_i[g];
      g_l[s * PIX + row] = l;
    }
    float linv[4];
#pragma unroll
    for (int r = 0; r < 4; ++r) linv[r] = 1.0f / __shfl(l, qd * 4 + r);
#pragma unroll
    for (int ct = 0; ct < 16; ++ct)
#pragma unroll
      for (int r = 0; r < 4; ++r) {
        const int qrow = q0 + g * 16 + qd * 4 + r;
        const int c = ct * 16 + c16;
        g_Of[((size_t)(s * PIX + b * NN + qrow)) * NC + c] = (f16)(acc[g][ct][r] * linv[r]);
      }
  }
}

// ---------------------------------------------------------------------------
// Merge NS partials (log2 domain): w_s = l_s * 2^(m_s - M) / den.
// 16B loads (half8 per split), 8 rows/block, grid PIX/8.
__global__ __launch_bounds__(256) void combine(const float* __restrict__ x,
                                               float* __restrict__ out) {
  const int tid  = threadIdx.x;
  const int lane = tid & 63;
  const int wid  = tid >> 6;
  const int row  = blockIdx.x * 8 + wid * 2 + (lane >> 5);
  const int c    = (lane & 31) * 8;

  float m[NS], l[NS], M = -1e30f;
#pragma unroll
  for (int s = 0; s < NS; ++s) {
    m[s] = g_m[s * PIX + row];
    l[s] = g_l[s * PIX + row];
    M = fmaxf(M, m[s]);
  }
  float w[NS], den = 0.f;
#pragma unroll
  for (int s = 0; s < NS; ++s) { w[s] = l[s] * exp2f(m[s] - M); den += w[s]; }
  const float inv = 1.0f / den;

  float a[8];
#pragma unroll
  for (int j = 0; j < 8; ++j) a[j] = 0.f;
#pragma unroll
  for (int s = 0; s < NS; ++s) {
    const half8 h = *(const half8*)&g_Of[((size_t)(s * PIX + row)) * NC + c];
    const float ws = w[s] * inv;
#pragma unroll
    for (int j = 0; j < 8; ++j) a[j] += ws * (float)h[j];
  }
  const floatx4 x0 = *(const floatx4*)&x[(size_t)row * NC + c];
  const floatx4 x1 = *(const floatx4*)&x[(size_t)row * NC + c + 4];
  floatx4 o0, o1;
#pragma unroll
  for (int j = 0; j < 4; ++j) { o0[j] = a[j] + x0[j]; o1[j] = a[j + 4] + x1[j]; }
  *(floatx4*)&out[(size_t)row * NC + c] = o0;
  *(floatx4*)&out[(size_t)row * NC + c + 4] = o1;
}

// ---------------------------------------------------------------------------
extern "C" void kernel_launch(void* const* d_in, const int* in_sizes, int n_in,
                              void* d_out, int out_size, void* d_ws, size_t ws_size,
                              hipStream_t stream) {
  (void)in_sizes; (void)n_in; (void)d_ws; (void)ws_size; (void)out_size;
  const float* x  = (const float*)d_in[0];
  const float* wq = (const float*)d_in[1];
  const float* bq = (const float*)d_in[2];
  const float* wk = (const float*)d_in[3];
  const float* bk = (const float*)d_in[4];
  const float* wv = (const float*)d_in[5];
  const float* bv = (const float*)d_in[6];
  float* out = (float*)d_out;

  hipLaunchKernelGGL(prep_weights, dim3(320), dim3(256), 0, stream, wq, wk, wv);
  hipLaunchKernelGGL(proj_qkv, dim3(256, 4), dim3(256), 0, stream, x, bq, bk, bv);
  hipLaunchKernelGGL(attn_split, dim3(NN / 128, NB, NS), dim3(256), 0, stream);
  hipLaunchKernelGGL(combine, dim3(PIX / 8), dim3(256), 0, stream, x, out);
}